// Round 5
// baseline (390.882 us; speedup 1.0000x reference)
//
#include <hip/hip_runtime.h>
#include <hip/hip_bf16.h>

#define M_ROWS 16384
#define D_DIM  1024
#define K_CB   4096

#define BM 256                             // z rows per block
#define BC 256                             // cb entries per chunk
#define BK 64
#define NS 8
#define COLS_PER_SPLIT (K_CB / NS)         // 512
#define NITER 16                           // 32 K-tiles, 2 per iteration
#define MBLOCKS (M_ROWS / BM)              // 64

typedef __attribute__((ext_vector_type(8))) short short8;
typedef __attribute__((ext_vector_type(4))) float f32x4;

static __device__ __forceinline__ unsigned short f2bf(float f) {
  unsigned u = __float_as_uint(f);
  unsigned r = ((u >> 16) & 1u) + 0x7FFFu;   // RNE
  return (unsigned short)((u + r) >> 16);
}

static __device__ __forceinline__ unsigned f2sortable(float f) {
  unsigned u = __float_as_uint(f);
  return (u & 0x80000000u) ? ~u : (u | 0x80000000u);
}

static __device__ __forceinline__ float sortable2f(unsigned s) {
  unsigned u = (s & 0x80000000u) ? (s ^ 0x80000000u) : ~s;
  return __uint_as_float(u);
}

static __device__ __forceinline__ void gload_lds16(const unsigned short* g, unsigned short* l) {
  __builtin_amdgcn_global_load_lds(
      (const __attribute__((address_space(1))) void*)g,
      (__attribute__((address_space(3))) void*)l, 16, 0, 0);
}

// ---------------- Kernel 1: l2-normalize rows -> bf16 ----------------
__global__ __launch_bounds__(256)
void k_normalize(const float* __restrict__ z, const float* __restrict__ cb,
                 unsigned short* __restrict__ zf, unsigned short* __restrict__ cbf) {
  const int bid = blockIdx.x;
  const float* src;
  unsigned short* dst;
  if (bid < M_ROWS) {
    src = z + (size_t)bid * D_DIM;
    dst = zf + (size_t)bid * D_DIM;
  } else {
    const int r = bid - M_ROWS;
    src = cb + (size_t)r * D_DIM;
    dst = cbf + (size_t)r * D_DIM;
  }
  const int t = threadIdx.x;
  const float4 v = ((const float4*)src)[t];
  float ss = v.x * v.x + v.y * v.y + v.z * v.z + v.w * v.w;
#pragma unroll
  for (int off = 32; off > 0; off >>= 1) ss += __shfl_down(ss, off, 64);
  __shared__ float sp[4];
  if ((t & 63) == 0) sp[t >> 6] = ss;
  __syncthreads();
  const float tot = sp[0] + sp[1] + sp[2] + sp[3];
  const float invn = 1.0f / sqrtf(tot + 1e-12f);
  ushort4 o;
  o.x = f2bf(v.x * invn);
  o.y = f2bf(v.y * invn);
  o.z = f2bf(v.z * invn);
  o.w = f2bf(v.w * invn);
  ((ushort4*)dst)[t] = o;
}

// ---------------- Kernel 2: 256x256 8-phase fused GEMM + register top-8 ----------------
// A = codebook tile (256 entries), B = z tile (256 rows), D-col = z row (lane&15).
// 8 waves (wc in {0,1} cb-dir x wz in {0..3} z-dir); per wave 128 cb x 64 z.
// LDS: Z[2][256][64] + C[2][256][64] bf16 = 128 KB (dynamic). Swizzle: 16B-slot
// s' = s ^ (row&7) (row stride 128 B) -> ds_read_b128 at the 8-lane/quad floor.
// Schedule/iteration (K-tiles 2it (buf0), 2it+1 (buf1)); stage = 1 half-tile
// (128 rows x 64) = 2 gload_lds/thread:
//   P1 rd cf[0-3]+zlo(buf0), stage Z h1(2it+1) | P2 rd zhi, stage C h0(2it+1)
//   P3 rd cf[4-7],        stage C h1(2it+1) | P4 ---,    stage Z h0(2it+2) CHK
//   P5-P8 mirror on buf1, staging (2it+2) halves then Z h0(2it+3)        CHK
// CHK = s_waitcnt vmcnt(2): of 10 outstanding loads the 8 oldest (the 4
// half-tiles read next phase-group) must land; 2 stay in flight.
__global__ __launch_bounds__(512, 2)
void k_gemm_topk8(const unsigned short* __restrict__ zf,
                  const unsigned short* __restrict__ cbf,
                  unsigned* __restrict__ part) {
  extern __shared__ __align__(16) unsigned short smem[];   // 131072 B
  unsigned short* sZ = smem;            // [2][16384] elems
  unsigned short* sC = smem + 32768;    // [2][16384] elems

  const int tid  = threadIdx.x;
  const int lane = tid & 63;
  const int wid  = tid >> 6;
  const int wc   = wid & 1;
  const int wz   = wid >> 1;
  const int lo   = lane & 15;
  const int hi   = lane >> 4;

  const int wgid  = (int)blockIdx.x;
  const int split = wgid & 7;          // xcd-resident 1MB codebook slab
  const int mtile = wgid >> 3;
  const int rbase = mtile * BM;
  const int cbase = split * COLS_PER_SPLIT;

  // fragment element offsets within one 16384-elem buffer (row&7 == lo&7)
  int cAddr[2], zAddr[2];
#pragma unroll
  for (int kk = 0; kk < 2; ++kk) {
    cAddr[kk] = (wc * 128 + lo) * 64 + ((((kk << 2) + hi) ^ (lo & 7)) << 3);
    zAddr[kk] = (wz * 64 + lo) * 64 + ((((kk << 2) + hi) ^ (lo & 7)) << 3);
  }

  // staging lane constants: thread covers slots tid and tid+512 of a half-tile
  const int srow = tid >> 3;           // 0..63
  const long stoff = (long)srow * D_DIM + (((tid & 7) ^ (srow & 7)) << 3);

  auto stageZ = [&](int half, int kg) {
    kg &= 31;
    const unsigned short* src = zf + (size_t)(rbase + half * 128) * D_DIM + ((kg & 15) << 6) + stoff;
    unsigned short* dst = sZ + (kg & 1) * 16384 + half * 8192 + tid * 8;
    gload_lds16(src, dst);
    gload_lds16(src + 64 * D_DIM, dst + 4096);
  };
  auto stageC = [&](int half, int kg) {
    kg &= 31;
    const unsigned short* src = cbf + (size_t)(cbase + (kg >> 4) * 256 + half * 128) * D_DIM + ((kg & 15) << 6) + stoff;
    unsigned short* dst = sC + (kg & 1) * 16384 + half * 8192 + tid * 8;
    gload_lds16(src, dst);
    gload_lds16(src + 64 * D_DIM, dst + 4096);
  };

  f32x4 acc[8][4];
#pragma unroll
  for (int mi = 0; mi < 8; ++mi)
#pragma unroll
    for (int nj = 0; nj < 4; ++nj) acc[mi][nj] = (f32x4){0.f, 0.f, 0.f, 0.f};

  unsigned tk[4][8];
  unsigned tkmin[4];
  float    tminf[4];
#pragma unroll
  for (int l = 0; l < 4; ++l) {
    tkmin[l] = 0u;
    tminf[l] = -__builtin_inff();
#pragma unroll
    for (int q = 0; q < 8; ++q) tk[l][q] = 0u;
  }

#define LOAD_CF(BUFOFF, MIB) do { \
  _Pragma("unroll") for (int mi = 0; mi < 4; ++mi) \
  _Pragma("unroll") for (int kk = 0; kk < 2; ++kk) \
    cfr[mi][kk] = *(const short8*)(sC + (BUFOFF) + cAddr[kk] + ((MIB) + mi) * 1024); \
} while (0)
#define LOAD_ZP(DST, BUFOFF, NJB) do { \
  _Pragma("unroll") for (int nj = 0; nj < 2; ++nj) \
  _Pragma("unroll") for (int kk = 0; kk < 2; ++kk) \
    DST[nj][kk] = *(const short8*)(sZ + (BUFOFF) + zAddr[kk] + ((NJB) + nj) * 1024); \
} while (0)
#define MFMA_Q(ZZ, MIB, NJB) do { \
  __builtin_amdgcn_s_setprio(1); \
  _Pragma("unroll") for (int mi = 0; mi < 4; ++mi) \
  _Pragma("unroll") for (int nj = 0; nj < 2; ++nj) \
  _Pragma("unroll") for (int kk = 0; kk < 2; ++kk) \
    acc[(MIB) + mi][(NJB) + nj] = __builtin_amdgcn_mfma_f32_16x16x32_bf16(cfr[mi][kk], ZZ[nj][kk], acc[(MIB) + mi][(NJB) + nj], 0, 0, 0); \
  __builtin_amdgcn_s_setprio(0); \
} while (0)
#define BAR_MID() do { __builtin_amdgcn_s_barrier(); \
  asm volatile("s_waitcnt lgkmcnt(0)" ::: "memory"); \
  __builtin_amdgcn_sched_barrier(0); } while (0)
#define BAR_END() do { __builtin_amdgcn_s_barrier(); } while (0)
#define BAR_END_CHK() do { asm volatile("s_waitcnt vmcnt(2)" ::: "memory"); \
  __builtin_amdgcn_s_barrier(); __builtin_amdgcn_sched_barrier(0); } while (0)

  // prologue: K-tile 0 fully + Z h0 of K-tile 1 (10 loads; 8 oldest must land)
  stageZ(0, 0); stageZ(1, 0); stageC(0, 0); stageC(1, 0);
  stageZ(0, 1);
  asm volatile("s_waitcnt vmcnt(2)" ::: "memory");
  __builtin_amdgcn_s_barrier();
  __builtin_amdgcn_sched_barrier(0);

  for (int it = 0; it < NITER; ++it) {
    const int kg1 = 2 * it + 1;
    short8 cfr[4][2], zlo[2][2], zhi[2][2];

    // P1
    LOAD_CF(16384 * 0, 0);
    LOAD_ZP(zlo, 16384 * 0, 0);
    stageZ(1, kg1);
    BAR_MID();
    MFMA_Q(zlo, 0, 0);
    BAR_END();
    // P2
    LOAD_ZP(zhi, 16384 * 0, 2);
    stageC(0, kg1);
    BAR_MID();
    MFMA_Q(zhi, 0, 2);
    BAR_END();
    // P3
    LOAD_CF(16384 * 0, 4);
    stageC(1, kg1);
    BAR_MID();
    MFMA_Q(zhi, 4, 2);
    BAR_END();
    // P4
    stageZ(0, kg1 + 1);
    BAR_MID();
    MFMA_Q(zlo, 4, 0);
    BAR_END_CHK();
    // P5
    LOAD_CF(16384, 0);
    LOAD_ZP(zlo, 16384, 0);
    stageZ(1, kg1 + 1);
    BAR_MID();
    MFMA_Q(zlo, 0, 0);
    BAR_END();
    // P6
    LOAD_ZP(zhi, 16384, 2);
    stageC(0, kg1 + 1);
    BAR_MID();
    MFMA_Q(zhi, 0, 2);
    BAR_END();
    // P7
    LOAD_CF(16384, 4);
    stageC(1, kg1 + 1);
    BAR_MID();
    MFMA_Q(zhi, 4, 2);
    BAR_END();
    // P8
    stageZ(0, kg1 + 2);
    BAR_MID();
    MFMA_Q(zlo, 4, 0);
    BAR_END_CHK();

    // chunk epilogue: lane-local top-8 insert over acc (no barriers)
    if ((it & 7) == 7) {
      const int cfb = cbase + (it >> 3) * 256 + wc * 128 + hi * 4;
#pragma unroll
      for (int nj = 0; nj < 4; ++nj) {
#pragma unroll
        for (int mi = 0; mi < 8; ++mi) {
#pragma unroll
          for (int r = 0; r < 4; ++r) {
            const float v = acc[mi][nj][r];
            // must be !(v <= t): tminf is NaN while table has empty slots ->
            // fall through to the exact u32 check ((v > NaN) starves; R2 bug).
            if (!(v <= tminf[nj])) {
              const unsigned key = (f2sortable(v) & ~0xFFFu) | (unsigned)(cfb + mi * 16 + r);
              if (key > tkmin[nj]) {
                int ms = 0;
                unsigned mv = tk[nj][0];
#pragma unroll
                for (int q = 1; q < 8; ++q) { if (tk[nj][q] < mv) { mv = tk[nj][q]; ms = q; } }
#pragma unroll
                for (int q = 0; q < 8; ++q) tk[nj][q] = (q == ms) ? key : tk[nj][q];
                mv = tk[nj][0];
#pragma unroll
                for (int q = 1; q < 8; ++q) mv = (tk[nj][q] < mv) ? tk[nj][q] : mv;
                tkmin[nj] = mv;
                tminf[nj] = sortable2f(mv & ~0xFFFu);
              }
            }
            acc[mi][nj][r] = 0.f;
          }
        }
      }
    }
  }

  // drain stray prefetches (they alias the merge region), then merge via LDS
  asm volatile("s_waitcnt vmcnt(0)" ::: "memory");
  __syncthreads();
  unsigned* mrg = (unsigned*)smem;     // [256][64] u32 = 64 KB
  {
    const int slot = wc * 4 + hi;
#pragma unroll
    for (int nj = 0; nj < 4; ++nj) {
      const int zrow = wz * 64 + nj * 16 + lo;
#pragma unroll
      for (int q = 0; q < 8; ++q) mrg[zrow * 64 + slot * 8 + q] = tk[nj][q];
    }
  }
  __syncthreads();
  if (tid < BM) {
    const unsigned* c = mrg + tid * 64;
    unsigned top[8];
#pragma unroll
    for (int p = 0; p < 8; ++p) top[p] = 0u;
    unsigned tmin = 0u;
    for (int q0 = 0; q0 < 64; ++q0) {
      const unsigned k = c[(q0 + tid) & 63];   // rotate to spread banks
      if (k > tmin) {
        int ms = 0;
        unsigned mv = top[0];
#pragma unroll
        for (int q = 1; q < 8; ++q) { if (top[q] < mv) { mv = top[q]; ms = q; } }
#pragma unroll
        for (int q = 0; q < 8; ++q) top[q] = (q == ms) ? k : top[q];
        mv = top[0];
#pragma unroll
        for (int q = 1; q < 8; ++q) mv = (top[q] < mv) ? top[q] : mv;
        tmin = mv;
      }
    }
    unsigned* dst = part + ((size_t)(rbase + tid) * NS + split) * 8;
#pragma unroll
    for (int p = 0; p < 8; ++p) dst[p] = top[p];
  }
}

// ---------------- Kernel 3: merge splits, softmax, gather E, gate ----------------
template<int NSP>
__global__ __launch_bounds__(256)
void k_gate(const unsigned* __restrict__ part, const float* __restrict__ target,
            const float* __restrict__ E, float* __restrict__ out) {
  constexpr int NK = NSP * 8;
  const int row = blockIdx.x;
  const int t = threadIdx.x;
  __shared__ float s_alpha[8];
  __shared__ int s_idx[8];
  __shared__ unsigned s_key[8];

  if (t < NK) {
    unsigned k = part[(size_t)row * NK + t];
#pragma unroll
    for (int p = 0; p < 8; ++p) {
      unsigned m = k;
#pragma unroll
      for (int off = NK / 2; off > 0; off >>= 1) {
        const unsigned o = __shfl_xor(m, off, NK);
        m = (m > o) ? m : o;
      }
      if (k == m) { s_key[p] = k; k = 0u; }  // keys distinct (idx in low bits)
    }
  }
  __syncthreads();
  if (t < 8) {
    const unsigned key = s_key[t];
    const float val  = 10.0f * sortable2f(key & ~0xFFFu);
    const float vmax = 10.0f * sortable2f(s_key[0] & ~0xFFFu);
    const float e = expf(val - vmax);
    float s = e;
#pragma unroll
    for (int off = 4; off > 0; off >>= 1) s += __shfl_xor(s, off, 8);
    s_alpha[t] = e / s;
    s_idx[t] = (int)(key & 0xFFFu);
  }
  __syncthreads();

  float4 g = {0.f, 0.f, 0.f, 0.f};
#pragma unroll
  for (int p = 0; p < 8; ++p) {
    const float a = s_alpha[p];
    const float4 e4 = ((const float4*)E)[(size_t)s_idx[p] * 256 + t];
    g.x += a * e4.x;
    g.y += a * e4.y;
    g.z += a * e4.z;
    g.w += a * e4.w;
  }
  const float4 tg = ((const float4*)target)[(size_t)row * 256 + t];
  float4 o;
  o.x = tg.x * (1.f + g.x);
  o.y = tg.y * (1.f + g.y);
  o.z = tg.z * (1.f + g.z);
  o.w = tg.w * (1.f + g.w);
  ((float4*)out)[(size_t)row * 256 + t] = o;
}

extern "C" void kernel_launch(void* const* d_in, const int* in_sizes, int n_in,
                              void* d_out, int out_size, void* d_ws, size_t ws_size,
                              hipStream_t stream) {
  const float* z      = (const float*)d_in[0];
  const float* target = (const float*)d_in[1];
  const float* cb     = (const float*)d_in[2];
  const float* E      = (const float*)d_in[3];
  float* out = (float*)d_out;

  // d_out doubles as scratch for the bf16 normalized matrices (dead before k_gate writes)
  unsigned short* zf  = (unsigned short*)d_out;                       // 32 MB
  unsigned short* cbf = (unsigned short*)((char*)d_out + 33554432);   // 8 MB @ +32MB
  unsigned* part = (unsigned*)d_ws;                                   // 4 MB (ws verified >= 4MB in R4)

  hipFuncSetAttribute((const void*)k_gemm_topk8,
                      hipFuncAttributeMaxDynamicSharedMemorySize, 131072);

  k_normalize<<<dim3(M_ROWS + K_CB), dim3(256), 0, stream>>>(z, cb, zf, cbf);
  k_gemm_topk8<<<dim3(MBLOCKS * NS), dim3(512), 131072, stream>>>(zf, cbf, part);
  k_gate<NS><<<dim3(M_ROWS), dim3(256), 0, stream>>>(part, target, E, out);
}

// Round 6
// 348.680 us; speedup vs baseline: 1.1210x; 1.1210x over previous
//
#include <hip/hip_runtime.h>
#include <hip/hip_bf16.h>

#define M_ROWS 16384
#define D_DIM  1024
#define K_CB   4096

#define BM 256                             // z rows per block
#define BK 32
#define NS 8
#define COLS_PER_SPLIT (K_CB / NS)         // 512
#define TOTAL_KT 64                        // 2 chunks x 32 K-tiles
#define MBLOCKS (M_ROWS / BM)              // 64

typedef __attribute__((ext_vector_type(8))) short short8;
typedef __attribute__((ext_vector_type(4))) float f32x4;

static __device__ __forceinline__ unsigned short f2bf(float f) {
  unsigned u = __float_as_uint(f);
  unsigned r = ((u >> 16) & 1u) + 0x7FFFu;   // RNE
  return (unsigned short)((u + r) >> 16);
}

static __device__ __forceinline__ unsigned f2sortable(float f) {
  unsigned u = __float_as_uint(f);
  return (u & 0x80000000u) ? ~u : (u | 0x80000000u);
}

static __device__ __forceinline__ float sortable2f(unsigned s) {
  unsigned u = (s & 0x80000000u) ? (s ^ 0x80000000u) : ~s;
  return __uint_as_float(u);
}

static __device__ __forceinline__ void gload_lds16(const unsigned short* g, unsigned short* l) {
  __builtin_amdgcn_global_load_lds(
      (const __attribute__((address_space(1))) void*)g,
      (__attribute__((address_space(3))) void*)l, 16, 0, 0);
}

// ---------------- Kernel 1: l2-normalize rows -> bf16 ----------------
__global__ __launch_bounds__(256)
void k_normalize(const float* __restrict__ z, const float* __restrict__ cb,
                 unsigned short* __restrict__ zf, unsigned short* __restrict__ cbf) {
  const int bid = blockIdx.x;
  const float* src;
  unsigned short* dst;
  if (bid < M_ROWS) {
    src = z + (size_t)bid * D_DIM;
    dst = zf + (size_t)bid * D_DIM;
  } else {
    const int r = bid - M_ROWS;
    src = cb + (size_t)r * D_DIM;
    dst = cbf + (size_t)r * D_DIM;
  }
  const int t = threadIdx.x;
  const float4 v = ((const float4*)src)[t];
  float ss = v.x * v.x + v.y * v.y + v.z * v.z + v.w * v.w;
#pragma unroll
  for (int off = 32; off > 0; off >>= 1) ss += __shfl_down(ss, off, 64);
  __shared__ float sp[4];
  if ((t & 63) == 0) sp[t >> 6] = ss;
  __syncthreads();
  const float tot = sp[0] + sp[1] + sp[2] + sp[3];
  const float invn = 1.0f / sqrtf(tot + 1e-12f);
  ushort4 o;
  o.x = f2bf(v.x * invn);
  o.y = f2bf(v.y * invn);
  o.z = f2bf(v.z * invn);
  o.w = f2bf(v.w * invn);
  ((ushort4*)dst)[t] = o;
}

// ---------------- Kernel 2: 256x256, BK=32, 4-slot ring, 2-phase/K-tile ----------------
// 8 waves (wc cb-dir x wz z-dir); per wave 128 cb x 64 z. K-tile = 256x32 bf16
// = 16 KB/slot; 4 slots/matrix ring = 128 KB LDS total.
// Ring: read tile t (slot t&3) while staging tile t+3 (slot (t-1)&3, last read
// at t-1: safe). vmcnt(8) at tile end keeps tiles t+2,t+3 in flight and forces
// t+1 (staged 6 phases earlier ~1800cy cover) landed. Stage never drains.
// Swizzle (R4-proven, conflict-free): 16B slot s' = s ^ ((row>>1)&3).
__global__ __launch_bounds__(512, 2)
void k_gemm_topk8(const unsigned short* __restrict__ zf,
                  const unsigned short* __restrict__ cbf,
                  unsigned* __restrict__ part) {
  extern __shared__ __align__(16) unsigned short smem[];   // 131072 B
  unsigned short* sZ = smem;            // 4 x 8192 elems
  unsigned short* sC = smem + 32768;    // 4 x 8192 elems

  const int tid  = threadIdx.x;
  const int lane = tid & 63;
  const int wid  = tid >> 6;
  const int wc   = wid & 1;
  const int wz   = wid >> 1;
  const int lo   = lane & 15;
  const int hi   = lane >> 4;

  const int wgid  = (int)blockIdx.x;
  const int split = wgid & 7;          // xcd-resident codebook slab
  const int mtile = wgid >> 3;
  const int rbase = mtile * BM;
  const int cbase = split * COLS_PER_SPLIT;

  // fragment byte-element offsets within a slot (row stride 32 elems = 64 B)
  int cAddr[8], zAddr[4];
  const int swz = (hi ^ ((lo >> 1) & 3)) << 3;
#pragma unroll
  for (int mi = 0; mi < 8; ++mi) cAddr[mi] = (wc * 128 + mi * 16 + lo) * BK + swz;
#pragma unroll
  for (int nj = 0; nj < 4; ++nj) zAddr[nj] = (wz * 64 + nj * 16 + lo) * BK + swz;

  // staging: thread covers 16B slots tid (row tid>>2) and tid+512 (row+128);
  // LDS dest linear, global source pre-swizzled with the same involution.
  const int srow = tid >> 2;
  const long stoff = (long)srow * D_DIM + (((tid & 3) ^ ((srow >> 1) & 3)) << 3);

  auto stageZ = [&](int kt) {
    const unsigned short* src = zf + (size_t)rbase * D_DIM + ((kt & 31) << 5) + stoff;
    unsigned short* dst = sZ + (kt & 3) * 8192 + tid * 8;
    gload_lds16(src, dst);
    gload_lds16(src + 128 * D_DIM, dst + 4096);
  };
  auto stageC = [&](int kt) {
    const unsigned short* src = cbf + (size_t)(cbase + (kt >> 5) * 256) * D_DIM + ((kt & 31) << 5) + stoff;
    unsigned short* dst = sC + (kt & 3) * 8192 + tid * 8;
    gload_lds16(src, dst);
    gload_lds16(src + 128 * D_DIM, dst + 4096);
  };

  f32x4 acc[8][4];
#pragma unroll
  for (int mi = 0; mi < 8; ++mi)
#pragma unroll
    for (int nj = 0; nj < 4; ++nj) acc[mi][nj] = (f32x4){0.f, 0.f, 0.f, 0.f};

  unsigned tk[4][8];
  unsigned tkmin[4];
  float    tminf[4];
#pragma unroll
  for (int l = 0; l < 4; ++l) {
    tkmin[l] = 0u;
    tminf[l] = -__builtin_inff();
#pragma unroll
    for (int q = 0; q < 8; ++q) tk[l][q] = 0u;
  }

  // prologue: stage tiles 0,1,2 (12 instrs); tile 0 (oldest 4) must land
  stageZ(0); stageC(0); stageZ(1); stageC(1); stageZ(2); stageC(2);
  asm volatile("s_waitcnt vmcnt(8)" ::: "memory");
  __builtin_amdgcn_s_barrier();
  __builtin_amdgcn_sched_barrier(0);

  for (int t = 0; t < TOTAL_KT; ++t) {
    const int sb = (t & 3) * 8192;
    short8 cfr[4], zr[4];

    // ---- Phase A: mi 0-3 x nj 0-3 ----
#pragma unroll
    for (int mi = 0; mi < 4; ++mi) cfr[mi] = *(const short8*)(sC + sb + cAddr[mi]);
#pragma unroll
    for (int nj = 0; nj < 4; ++nj) zr[nj] = *(const short8*)(sZ + sb + zAddr[nj]);
    if (t <= TOTAL_KT - 4) stageZ(t + 3);
    __builtin_amdgcn_s_barrier();
    asm volatile("s_waitcnt lgkmcnt(0)" ::: "memory");
    __builtin_amdgcn_sched_barrier(0);
    __builtin_amdgcn_s_setprio(1);
#pragma unroll
    for (int mi = 0; mi < 4; ++mi)
#pragma unroll
      for (int nj = 0; nj < 4; ++nj)
        acc[mi][nj] = __builtin_amdgcn_mfma_f32_16x16x32_bf16(cfr[mi], zr[nj], acc[mi][nj], 0, 0, 0);
    __builtin_amdgcn_s_setprio(0);
    __builtin_amdgcn_s_barrier();

    // ---- Phase B: mi 4-7 x nj 0-3 ----
#pragma unroll
    for (int mi = 0; mi < 4; ++mi) cfr[mi] = *(const short8*)(sC + sb + cAddr[4 + mi]);
    if (t <= TOTAL_KT - 4) stageC(t + 3);
    __builtin_amdgcn_s_barrier();
    asm volatile("s_waitcnt lgkmcnt(0)" ::: "memory");
    __builtin_amdgcn_sched_barrier(0);
    __builtin_amdgcn_s_setprio(1);
#pragma unroll
    for (int mi = 0; mi < 4; ++mi)
#pragma unroll
      for (int nj = 0; nj < 4; ++nj)
        acc[4 + mi][nj] = __builtin_amdgcn_mfma_f32_16x16x32_bf16(cfr[mi], zr[nj], acc[4 + mi][nj], 0, 0, 0);
    __builtin_amdgcn_s_setprio(0);
    // tile-boundary CHK: allow tiles t+2,t+3 (8 instrs) in flight; force t+1
    // landed. Tail: fewer groups exist, tighten (t=61 -> 4, t>=62 -> 0).
    if (t <= TOTAL_KT - 4)      asm volatile("s_waitcnt vmcnt(8)" ::: "memory");
    else if (t == TOTAL_KT - 3) asm volatile("s_waitcnt vmcnt(4)" ::: "memory");
    else                        asm volatile("s_waitcnt vmcnt(0)" ::: "memory");
    __builtin_amdgcn_s_barrier();
    __builtin_amdgcn_sched_barrier(0);

    // chunk epilogue: lane-local top-8 insert over acc (no barriers)
    if (t == 31 || t == TOTAL_KT - 1) {
      const int cfb = cbase + (t >> 5) * 256 + wc * 128 + hi * 4;
#pragma unroll
      for (int nj = 0; nj < 4; ++nj) {
#pragma unroll
        for (int mi = 0; mi < 8; ++mi) {
#pragma unroll
          for (int r = 0; r < 4; ++r) {
            const float v = acc[mi][nj][r];
            // must be !(v <= t): tminf is NaN while table has empty slots ->
            // fall through to the exact u32 check ((v > NaN) starves; R2 bug).
            if (!(v <= tminf[nj])) {
              const unsigned key = (f2sortable(v) & ~0xFFFu) | (unsigned)(cfb + mi * 16 + r);
              if (key > tkmin[nj]) {
                int ms = 0;
                unsigned mv = tk[nj][0];
#pragma unroll
                for (int q = 1; q < 8; ++q) { if (tk[nj][q] < mv) { mv = tk[nj][q]; ms = q; } }
#pragma unroll
                for (int q = 0; q < 8; ++q) tk[nj][q] = (q == ms) ? key : tk[nj][q];
                mv = tk[nj][0];
#pragma unroll
                for (int q = 1; q < 8; ++q) mv = (tk[nj][q] < mv) ? tk[nj][q] : mv;
                tkmin[nj] = mv;
                tminf[nj] = sortable2f(mv & ~0xFFFu);
              }
            }
            acc[mi][nj][r] = 0.f;
          }
        }
      }
    }
  }

  // merge via LDS (overwrites ring; all loads drained by final vmcnt(0))
  __syncthreads();
  unsigned* mrg = (unsigned*)smem;     // [256][64] u32 = 64 KB
  {
    const int slot = wc * 4 + hi;
#pragma unroll
    for (int nj = 0; nj < 4; ++nj) {
      const int zrow = wz * 64 + nj * 16 + lo;
#pragma unroll
      for (int q = 0; q < 8; ++q) mrg[zrow * 64 + slot * 8 + q] = tk[nj][q];
    }
  }
  __syncthreads();
  if (tid < BM) {
    const unsigned* c = mrg + tid * 64;
    unsigned top[8];
#pragma unroll
    for (int p = 0; p < 8; ++p) top[p] = 0u;
    unsigned tmin = 0u;
    for (int q0 = 0; q0 < 64; ++q0) {
      const unsigned k = c[(q0 + tid) & 63];   // rotate to spread banks
      if (k > tmin) {
        int ms = 0;
        unsigned mv = top[0];
#pragma unroll
        for (int q = 1; q < 8; ++q) { if (top[q] < mv) { mv = top[q]; ms = q; } }
#pragma unroll
        for (int q = 0; q < 8; ++q) top[q] = (q == ms) ? k : top[q];
        mv = top[0];
#pragma unroll
        for (int q = 1; q < 8; ++q) mv = (top[q] < mv) ? top[q] : mv;
        tmin = mv;
      }
    }
    unsigned* dst = part + ((size_t)(rbase + tid) * NS + split) * 8;
#pragma unroll
    for (int p = 0; p < 8; ++p) dst[p] = top[p];
  }
}

// ---------------- Kernel 3: merge splits, softmax, gather E, gate ----------------
template<int NSP>
__global__ __launch_bounds__(256)
void k_gate(const unsigned* __restrict__ part, const float* __restrict__ target,
            const float* __restrict__ E, float* __restrict__ out) {
  constexpr int NK = NSP * 8;
  const int row = blockIdx.x;
  const int t = threadIdx.x;
  __shared__ float s_alpha[8];
  __shared__ int s_idx[8];
  __shared__ unsigned s_key[8];

  if (t < NK) {
    unsigned k = part[(size_t)row * NK + t];
#pragma unroll
    for (int p = 0; p < 8; ++p) {
      unsigned m = k;
#pragma unroll
      for (int off = NK / 2; off > 0; off >>= 1) {
        const unsigned o = __shfl_xor(m, off, NK);
        m = (m > o) ? m : o;
      }
      if (k == m) { s_key[p] = k; k = 0u; }  // keys distinct (idx in low bits)
    }
  }
  __syncthreads();
  if (t < 8) {
    const unsigned key = s_key[t];
    const float val  = 10.0f * sortable2f(key & ~0xFFFu);
    const float vmax = 10.0f * sortable2f(s_key[0] & ~0xFFFu);
    const float e = expf(val - vmax);
    float s = e;
#pragma unroll
    for (int off = 4; off > 0; off >>= 1) s += __shfl_xor(s, off, 8);
    s_alpha[t] = e / s;
    s_idx[t] = (int)(key & 0xFFFu);
  }
  __syncthreads();

  float4 g = {0.f, 0.f, 0.f, 0.f};
#pragma unroll
  for (int p = 0; p < 8; ++p) {
    const float a = s_alpha[p];
    const float4 e4 = ((const float4*)E)[(size_t)s_idx[p] * 256 + t];
    g.x += a * e4.x;
    g.y += a * e4.y;
    g.z += a * e4.z;
    g.w += a * e4.w;
  }
  const float4 tg = ((const float4*)target)[(size_t)row * 256 + t];
  float4 o;
  o.x = tg.x * (1.f + g.x);
  o.y = tg.y * (1.f + g.y);
  o.z = tg.z * (1.f + g.z);
  o.w = tg.w * (1.f + g.w);
  ((float4*)out)[(size_t)row * 256 + t] = o;
}

extern "C" void kernel_launch(void* const* d_in, const int* in_sizes, int n_in,
                              void* d_out, int out_size, void* d_ws, size_t ws_size,
                              hipStream_t stream) {
  const float* z      = (const float*)d_in[0];
  const float* target = (const float*)d_in[1];
  const float* cb     = (const float*)d_in[2];
  const float* E      = (const float*)d_in[3];
  float* out = (float*)d_out;

  // d_out doubles as scratch for the bf16 normalized matrices (dead before k_gate writes)
  unsigned short* zf  = (unsigned short*)d_out;                       // 32 MB
  unsigned short* cbf = (unsigned short*)((char*)d_out + 33554432);   // 8 MB @ +32MB
  unsigned* part = (unsigned*)d_ws;                                   // 4 MB

  hipFuncSetAttribute((const void*)k_gemm_topk8,
                      hipFuncAttributeMaxDynamicSharedMemorySize, 131072);

  k_normalize<<<dim3(M_ROWS + K_CB), dim3(256), 0, stream>>>(z, cb, zf, cbf);
  k_gemm_topk8<<<dim3(MBLOCKS * NS), dim3(512), 131072, stream>>>(zf, cbf, part);
  k_gate<NS><<<dim3(M_ROWS), dim3(256), 0, stream>>>(part, target, E, out);
}

// Round 8
// 316.457 us; speedup vs baseline: 1.2352x; 1.1018x over previous
//
#include <hip/hip_runtime.h>
#include <hip/hip_bf16.h>

#define M_ROWS 16384
#define D_DIM  1024
#define K_CB   4096

#define MTILE  128               // z rows per block
#define BK     32
#define NS     8
#define COLS_PER_SPLIT (K_CB / NS)         // 512
#define KSTEPS (D_DIM / BK)                // 32
#define GITERS (4 * KSTEPS)                // 4 chunks of 128 cb x 32 K-steps
#define MBLOCKS (M_ROWS / MTILE)           // 128

typedef __attribute__((ext_vector_type(8))) short short8;
typedef __attribute__((ext_vector_type(16))) float f32x16;

static __device__ __forceinline__ unsigned short f2bf(float f) {
  unsigned u = __float_as_uint(f);
  unsigned r = ((u >> 16) & 1u) + 0x7FFFu;   // RNE
  return (unsigned short)((u + r) >> 16);
}

static __device__ __forceinline__ unsigned f2sortable(float f) {
  unsigned u = __float_as_uint(f);
  return (u & 0x80000000u) ? ~u : (u | 0x80000000u);
}

static __device__ __forceinline__ float sortable2f(unsigned s) {
  unsigned u = (s & 0x80000000u) ? (s ^ 0x80000000u) : ~s;
  return __uint_as_float(u);
}

static __device__ __forceinline__ void gload_lds16(const unsigned short* g, unsigned short* l) {
  __builtin_amdgcn_global_load_lds(
      (const __attribute__((address_space(1))) void*)g,
      (__attribute__((address_space(3))) void*)l, 16, 0, 0);
}

// ---------------- Kernel 1: l2-normalize rows -> bf16 ----------------
__global__ __launch_bounds__(256)
void k_normalize(const float* __restrict__ z, const float* __restrict__ cb,
                 unsigned short* __restrict__ zf, unsigned short* __restrict__ cbf) {
  const int bid = blockIdx.x;
  const float* src;
  unsigned short* dst;
  if (bid < M_ROWS) {
    src = z + (size_t)bid * D_DIM;
    dst = zf + (size_t)bid * D_DIM;
  } else {
    const int r = bid - M_ROWS;
    src = cb + (size_t)r * D_DIM;
    dst = cbf + (size_t)r * D_DIM;
  }
  const int t = threadIdx.x;
  const float4 v = ((const float4*)src)[t];
  float ss = v.x * v.x + v.y * v.y + v.z * v.z + v.w * v.w;
#pragma unroll
  for (int off = 32; off > 0; off >>= 1) ss += __shfl_down(ss, off, 64);
  __shared__ float sp[4];
  if ((t & 63) == 0) sp[t >> 6] = ss;
  __syncthreads();
  const float tot = sp[0] + sp[1] + sp[2] + sp[3];
  const float invn = 1.0f / sqrtf(tot + 1e-12f);
  ushort4 o;
  o.x = f2bf(v.x * invn);
  o.y = f2bf(v.y * invn);
  o.z = f2bf(v.z * invn);
  o.w = f2bf(v.w * invn);
  ((ushort4*)dst)[t] = o;
}

// ---------------- Kernel 2: 128x128 tile, 32x32x16 MFMA, compiler-scheduled ----------------
// m97-style 2-barrier loop; 4 waves (wc cb-dir x wzz z-dir), per wave 64cb x 64z
// as 2x2 MFMA-32 tiles. Swapped operands (A=codebook, B=z): D col = lane&31 =
// z row -> top-8 is lane-local (tk[2][8]). 32 KB LDS -> 3 blocks/CU
// (cross-block overlap hides barrier drains; the 1-block/CU lockstep of R5/R6
// capped MfmaUtil at 16%). NOTE: no LDS pointer arrays (R7 compile error:
// addrspacecast static initializer) - buffer selection via inline offsets.
__global__ __launch_bounds__(256, 3)
void k_gemm_topk(const unsigned short* __restrict__ zf,
                 const unsigned short* __restrict__ cbf,
                 unsigned* __restrict__ part) {
  __shared__ __align__(16) unsigned short smem[16384];  // 32 KB: Z dbuf | C dbuf

  const int tid  = threadIdx.x;
  const int lane = tid & 63;
  const int wid  = tid >> 6;
  const int wc   = wid & 1;    // cb 64-block
  const int wzz  = wid >> 1;   // z 64-block
  const int l31  = lane & 31;
  const int l5   = lane >> 5;

  const int wgid  = (int)blockIdx.x;
  const int split = wgid & 7;          // xcd-resident codebook slab
  const int mtile = wgid >> 3;
  const int rbase = mtile * MTILE;
  const int cbase = split * COLS_PER_SPLIT;

  // fragment elem offsets: row r, 16B slot s = kk*2 + l5, swizzled s^((r>>1)&3)
  int cAddr[2][2], zAddr[2][2];
#pragma unroll
  for (int mi = 0; mi < 2; ++mi) {
    const int r = wc * 64 + mi * 32 + l31;
#pragma unroll
    for (int kk = 0; kk < 2; ++kk)
      cAddr[mi][kk] = r * BK + ((((kk << 1) + l5) ^ ((r >> 1) & 3)) << 3);
  }
#pragma unroll
  for (int nj = 0; nj < 2; ++nj) {
    const int r = wzz * 64 + nj * 32 + l31;
#pragma unroll
    for (int kk = 0; kk < 2; ++kk)
      zAddr[nj][kk] = r * BK + ((((kk << 1) + l5) ^ ((r >> 1) & 3)) << 3);
  }

  // staging: thread -> 16B slot tid (row tid>>2, kslot tid&3), LDS linear,
  // global source pre-swizzled with the same involution. (row+64 keeps swz.)
  const int srow = tid >> 2;
  const long stoff = (long)srow * D_DIM + (((tid & 3) ^ ((srow >> 1) & 3)) << 3);

  f32x16 acc[2][2];
#pragma unroll
  for (int mi = 0; mi < 2; ++mi)
#pragma unroll
    for (int nj = 0; nj < 2; ++nj)
#pragma unroll
      for (int r = 0; r < 16; ++r) acc[mi][nj][r] = 0.f;

  unsigned tk[2][8];
  unsigned tkmin[2];
  float    tminf[2];
#pragma unroll
  for (int l = 0; l < 2; ++l) {
    tkmin[l] = 0u;
    tminf[l] = -__builtin_inff();
#pragma unroll
    for (int q = 0; q < 8; ++q) tk[l][q] = 0u;
  }

  auto STAGE = [&](int g1) {
    const int zb = (g1 & 1) ? 4096 : 0;
    const int cb2 = 8192 + zb;
    const long kb = (long)((g1 & (KSTEPS - 1)) << 5);
    const unsigned short* zs = zf + (size_t)rbase * D_DIM + kb + stoff;
    const unsigned short* cs = cbf + (size_t)(cbase + (g1 >> 5) * MTILE) * D_DIM + kb + stoff;
    gload_lds16(zs,               smem + zb + tid * 8);
    gload_lds16(zs + 64 * D_DIM,  smem + zb + 2048 + tid * 8);
    gload_lds16(cs,               smem + cb2 + tid * 8);
    gload_lds16(cs + 64 * D_DIM,  smem + cb2 + 2048 + tid * 8);
  };

  STAGE(0);
  __syncthreads();

  for (int g = 0; g < GITERS; ++g) {
    if (g + 1 < GITERS) STAGE(g + 1);
    {
      const unsigned short* Z = smem + ((g & 1) ? 4096 : 0);
      const unsigned short* C = Z + 8192;
      short8 cf[2][2], zr[2][2];
#pragma unroll
      for (int mi = 0; mi < 2; ++mi)
#pragma unroll
        for (int kk = 0; kk < 2; ++kk) cf[mi][kk] = *(const short8*)(C + cAddr[mi][kk]);
#pragma unroll
      for (int nj = 0; nj < 2; ++nj)
#pragma unroll
        for (int kk = 0; kk < 2; ++kk) zr[nj][kk] = *(const short8*)(Z + zAddr[nj][kk]);
#pragma unroll
      for (int kk = 0; kk < 2; ++kk)
#pragma unroll
        for (int mi = 0; mi < 2; ++mi)
#pragma unroll
          for (int nj = 0; nj < 2; ++nj)
            acc[mi][nj] = __builtin_amdgcn_mfma_f32_32x32x16_bf16(
                cf[mi][kk], zr[nj][kk], acc[mi][nj], 0, 0, 0);
    }

    // chunk epilogue every 32 K-steps: lane-local top-8 over 2x2x16 acc
    if ((g & (KSTEPS - 1)) == (KSTEPS - 1)) {
      const int cfb0 = cbase + (g >> 5) * MTILE + wc * 64 + l5 * 4;
#pragma unroll
      for (int nj = 0; nj < 2; ++nj) {
#pragma unroll
        for (int mi = 0; mi < 2; ++mi) {
#pragma unroll
          for (int r = 0; r < 16; ++r) {
            const float v = acc[mi][nj][r];
            // must be !(v <= t): tminf is NaN while table has empty slots ->
            // fall through to exact u32 check ((v > NaN) starves; R2 bug).
            if (!(v <= tminf[nj])) {
              // 32x32 C/D: cb = (r&3) + 8*(r>>2) + 4*l5 within the mi-block
              const unsigned idx = (unsigned)(cfb0 + mi * 32 + (r & 3) + ((r >> 2) << 3));
              const unsigned key = (f2sortable(v) & ~0xFFFu) | idx;
              if (key > tkmin[nj]) {
                int ms = 0;
                unsigned mv = tk[nj][0];
#pragma unroll
                for (int q = 1; q < 8; ++q) { if (tk[nj][q] < mv) { mv = tk[nj][q]; ms = q; } }
#pragma unroll
                for (int q = 0; q < 8; ++q) tk[nj][q] = (q == ms) ? key : tk[nj][q];
                mv = tk[nj][0];
#pragma unroll
                for (int q = 1; q < 8; ++q) mv = (tk[nj][q] < mv) ? tk[nj][q] : mv;
                tkmin[nj] = mv;
                tminf[nj] = sortable2f(mv & ~0xFFFu);
              }
            }
            acc[mi][nj][r] = 0.f;
          }
        }
      }
    }
    __syncthreads();
  }

  // merge: per z row 4 contributors (wc x l5) x 8 keys -> LDS, then top-8 scan
  unsigned* mrg = (unsigned*)smem;     // [128][33] u32 = 16.9 KB
  {
    const int slot = (wc * 2 + l5) * 8;
#pragma unroll
    for (int nj = 0; nj < 2; ++nj) {
      const int zrow = wzz * 64 + nj * 32 + l31;
#pragma unroll
      for (int q = 0; q < 8; ++q) mrg[zrow * 33 + slot + q] = tk[nj][q];
    }
  }
  __syncthreads();
  if (tid < MTILE) {
    const unsigned* c = mrg + tid * 33;
    unsigned top[8];
#pragma unroll
    for (int p = 0; p < 8; ++p) top[p] = 0u;
    unsigned tmin = 0u;
    for (int q0 = 0; q0 < 32; ++q0) {
      const unsigned k = c[(q0 + tid) & 31];   // rotate to spread banks
      if (k > tmin) {
        int ms = 0;
        unsigned mv = top[0];
#pragma unroll
        for (int q = 1; q < 8; ++q) { if (top[q] < mv) { mv = top[q]; ms = q; } }
#pragma unroll
        for (int q = 0; q < 8; ++q) top[q] = (q == ms) ? k : top[q];
        mv = top[0];
#pragma unroll
        for (int q = 1; q < 8; ++q) mv = (top[q] < mv) ? top[q] : mv;
        tmin = mv;
      }
    }
    unsigned* dst = part + ((size_t)(rbase + tid) * NS + split) * 8;
#pragma unroll
    for (int p = 0; p < 8; ++p) dst[p] = top[p];
  }
}

// ---------------- Kernel 3: merge splits, softmax, gather E, gate ----------------
template<int NSP>
__global__ __launch_bounds__(256)
void k_gate(const unsigned* __restrict__ part, const float* __restrict__ target,
            const float* __restrict__ E, float* __restrict__ out) {
  constexpr int NK = NSP * 8;
  const int row = blockIdx.x;
  const int t = threadIdx.x;
  __shared__ float s_alpha[8];
  __shared__ int s_idx[8];
  __shared__ unsigned s_key[8];

  if (t < NK) {
    unsigned k = part[(size_t)row * NK + t];
#pragma unroll
    for (int p = 0; p < 8; ++p) {
      unsigned m = k;
#pragma unroll
      for (int off = NK / 2; off > 0; off >>= 1) {
        const unsigned o = __shfl_xor(m, off, NK);
        m = (m > o) ? m : o;
      }
      if (k == m) { s_key[p] = k; k = 0u; }  // keys distinct (idx in low bits)
    }
  }
  __syncthreads();
  if (t < 8) {
    const unsigned key = s_key[t];
    const float val  = 10.0f * sortable2f(key & ~0xFFFu);
    const float vmax = 10.0f * sortable2f(s_key[0] & ~0xFFFu);
    const float e = expf(val - vmax);
    float s = e;
#pragma unroll
    for (int off = 4; off > 0; off >>= 1) s += __shfl_xor(s, off, 8);
    s_alpha[t] = e / s;
    s_idx[t] = (int)(key & 0xFFFu);
  }
  __syncthreads();

  float4 g = {0.f, 0.f, 0.f, 0.f};
#pragma unroll
  for (int p = 0; p < 8; ++p) {
    const float a = s_alpha[p];
    const float4 e4 = ((const float4*)E)[(size_t)s_idx[p] * 256 + t];
    g.x += a * e4.x;
    g.y += a * e4.y;
    g.z += a * e4.z;
    g.w += a * e4.w;
  }
  const float4 tg = ((const float4*)target)[(size_t)row * 256 + t];
  float4 o;
  o.x = tg.x * (1.f + g.x);
  o.y = tg.y * (1.f + g.y);
  o.z = tg.z * (1.f + g.z);
  o.w = tg.w * (1.f + g.w);
  ((float4*)out)[(size_t)row * 256 + t] = o;
}

extern "C" void kernel_launch(void* const* d_in, const int* in_sizes, int n_in,
                              void* d_out, int out_size, void* d_ws, size_t ws_size,
                              hipStream_t stream) {
  const float* z      = (const float*)d_in[0];
  const float* target = (const float*)d_in[1];
  const float* cb     = (const float*)d_in[2];
  const float* E      = (const float*)d_in[3];
  float* out = (float*)d_out;

  // d_out doubles as scratch for the bf16 normalized matrices (dead before k_gate writes)
  unsigned short* zf  = (unsigned short*)d_out;                       // 32 MB
  unsigned short* cbf = (unsigned short*)((char*)d_out + 33554432);   // 8 MB @ +32MB
  unsigned* part = (unsigned*)d_ws;                                   // 4 MB

  k_normalize<<<dim3(M_ROWS + K_CB), dim3(256), 0, stream>>>(z, cb, zf, cbf);
  k_gemm_topk<<<dim3(MBLOCKS * NS), dim3(256), 0, stream>>>(zf, cbf, part);
  k_gate<NS><<<dim3(M_ROWS), dim3(256), 0, stream>>>(part, target, E, out);
}

// Round 9
// 313.316 us; speedup vs baseline: 1.2476x; 1.0100x over previous
//
#include <hip/hip_runtime.h>
#include <hip/hip_bf16.h>

#define M_ROWS 16384
#define D_DIM  1024
#define K_CB   4096

#define MTILE  128               // z rows per block
#define BK     32
#define NS     8
#define COLS_PER_SPLIT (K_CB / NS)         // 512
#define KSTEPS (D_DIM / BK)                // 32
#define GITERS (4 * KSTEPS)                // 4 chunks of 128 cb x 32 K-steps
#define MBLOCKS (M_ROWS / MTILE)           // 128

typedef __attribute__((ext_vector_type(8))) short short8;
typedef __attribute__((ext_vector_type(16))) float f32x16;

static __device__ __forceinline__ unsigned short f2bf(float f) {
  unsigned u = __float_as_uint(f);
  unsigned r = ((u >> 16) & 1u) + 0x7FFFu;   // RNE
  return (unsigned short)((u + r) >> 16);
}

static __device__ __forceinline__ unsigned f2sortable(float f) {
  unsigned u = __float_as_uint(f);
  return (u & 0x80000000u) ? ~u : (u | 0x80000000u);
}

static __device__ __forceinline__ float sortable2f(unsigned s) {
  unsigned u = (s & 0x80000000u) ? (s ^ 0x80000000u) : ~s;
  return __uint_as_float(u);
}

static __device__ __forceinline__ void gload_lds16(const unsigned short* g, unsigned short* l) {
  __builtin_amdgcn_global_load_lds(
      (const __attribute__((address_space(1))) void*)g,
      (__attribute__((address_space(3))) void*)l, 16, 0, 0);
}

// ---------------- Kernel 1: l2-normalize rows -> bf16 ----------------
__global__ __launch_bounds__(256)
void k_normalize(const float* __restrict__ z, const float* __restrict__ cb,
                 unsigned short* __restrict__ zf, unsigned short* __restrict__ cbf) {
  const int bid = blockIdx.x;
  const float* src;
  unsigned short* dst;
  if (bid < M_ROWS) {
    src = z + (size_t)bid * D_DIM;
    dst = zf + (size_t)bid * D_DIM;
  } else {
    const int r = bid - M_ROWS;
    src = cb + (size_t)r * D_DIM;
    dst = cbf + (size_t)r * D_DIM;
  }
  const int t = threadIdx.x;
  const float4 v = ((const float4*)src)[t];
  float ss = v.x * v.x + v.y * v.y + v.z * v.z + v.w * v.w;
#pragma unroll
  for (int off = 32; off > 0; off >>= 1) ss += __shfl_down(ss, off, 64);
  __shared__ float sp[4];
  if ((t & 63) == 0) sp[t >> 6] = ss;
  __syncthreads();
  const float tot = sp[0] + sp[1] + sp[2] + sp[3];
  const float invn = 1.0f / sqrtf(tot + 1e-12f);
  ushort4 o;
  o.x = f2bf(v.x * invn);
  o.y = f2bf(v.y * invn);
  o.z = f2bf(v.z * invn);
  o.w = f2bf(v.w * invn);
  ((ushort4*)dst)[t] = o;
}

// ---------------- Kernel 2: 128x128 tile, 32x32x16 MFMA, affine staging ----------------
// m97-style 1-barrier/K-step loop, unrolled x2 (compile-time buffer parity).
// Staging addresses are maintained as running pointers (+=32/step; Z wraps
// -1024 and C jumps +128*D-1024 at chunk boundaries) -- the R8 per-iter
// address recomputation was ~half of VALUBusy=47%.
// 4 blocks/CU (launch_bounds(256,4): 60 VGPR + 64 acc = 124 <= 128 cap).
__global__ __launch_bounds__(256, 4)
void k_gemm_topk(const unsigned short* __restrict__ zf,
                 const unsigned short* __restrict__ cbf,
                 unsigned* __restrict__ part) {
  __shared__ __align__(16) unsigned short smem[16384];  // 32 KB: {Z0,Z1,C0,C1} 8KB each

  const int tid  = threadIdx.x;
  const int lane = tid & 63;
  const int wid  = tid >> 6;
  const int wc   = wid & 1;    // cb 64-block
  const int wzz  = wid >> 1;   // z 64-block
  const int l31  = lane & 31;
  const int l5   = lane >> 5;

  const int wgid  = (int)blockIdx.x;
  const int split = wgid & 7;          // xcd-resident codebook slab
  const int mtile = wgid >> 3;
  const int rbase = mtile * MTILE;
  const int cbase = split * COLS_PER_SPLIT;

  // fragment elem offsets: row r, 16B slot s = kk*2 + l5, swizzled s^((r>>1)&3)
  int cAddr[2][2], zAddr[2][2];
#pragma unroll
  for (int mi = 0; mi < 2; ++mi) {
    const int r = wc * 64 + mi * 32 + l31;
#pragma unroll
    for (int kk = 0; kk < 2; ++kk)
      cAddr[mi][kk] = r * BK + ((((kk << 1) + l5) ^ ((r >> 1) & 3)) << 3);
  }
#pragma unroll
  for (int nj = 0; nj < 2; ++nj) {
    const int r = wzz * 64 + nj * 32 + l31;
#pragma unroll
    for (int kk = 0; kk < 2; ++kk)
      zAddr[nj][kk] = r * BK + ((((kk << 1) + l5) ^ ((r >> 1) & 3)) << 3);
  }

  // staging: thread -> 16B slot tid (row tid>>2, kslot tid&3), LDS linear,
  // global source pre-swizzled with the same involution. (row+64 keeps swz.)
  const int srow = tid >> 2;
  const long stoff = (long)srow * D_DIM + (((tid & 3) ^ ((srow >> 1) & 3)) << 3);

  // running stage pointers (point at the NEXT K-step to stage)
  const unsigned short* zsp = zf + (size_t)rbase * D_DIM + stoff;
  const unsigned short* csp = cbf + (size_t)cbase * D_DIM + stoff;

  f32x16 acc[2][2];
#pragma unroll
  for (int mi = 0; mi < 2; ++mi)
#pragma unroll
    for (int nj = 0; nj < 2; ++nj)
#pragma unroll
      for (int r = 0; r < 16; ++r) acc[mi][nj][r] = 0.f;

  unsigned tk[2][8];
  unsigned tkmin[2];
  float    tminf[2];
#pragma unroll
  for (int l = 0; l < 2; ++l) {
    tkmin[l] = 0u;
    tminf[l] = -__builtin_inff();
#pragma unroll
    for (int q = 0; q < 8; ++q) tk[l][q] = 0u;
  }

  // zb = Z buffer elem offset (0 or 4096); C buffer = zb + 8192
  auto STAGE = [&](int zb) {
    gload_lds16(zsp,              smem + zb + tid * 8);
    gload_lds16(zsp + 64 * D_DIM, smem + zb + 2048 + tid * 8);
    gload_lds16(csp,              smem + zb + 8192 + tid * 8);
    gload_lds16(csp + 64 * D_DIM, smem + zb + 8192 + 2048 + tid * 8);
  };
  auto COMPUTE = [&](int zb) {
    const unsigned short* Z = smem + zb;
    const unsigned short* C = Z + 8192;
    short8 cf[2][2], zr[2][2];
#pragma unroll
    for (int mi = 0; mi < 2; ++mi)
#pragma unroll
      for (int kk = 0; kk < 2; ++kk) cf[mi][kk] = *(const short8*)(C + cAddr[mi][kk]);
#pragma unroll
    for (int nj = 0; nj < 2; ++nj)
#pragma unroll
      for (int kk = 0; kk < 2; ++kk) zr[nj][kk] = *(const short8*)(Z + zAddr[nj][kk]);
#pragma unroll
    for (int kk = 0; kk < 2; ++kk)
#pragma unroll
      for (int mi = 0; mi < 2; ++mi)
#pragma unroll
        for (int nj = 0; nj < 2; ++nj)
          acc[mi][nj] = __builtin_amdgcn_mfma_f32_32x32x16_bf16(
              cf[mi][kk], zr[nj][kk], acc[mi][nj], 0, 0, 0);
  };
  auto EPILOGUE = [&](int chunk) {
    const int cfb0 = cbase + chunk * MTILE + wc * 64 + l5 * 4;
#pragma unroll
    for (int nj = 0; nj < 2; ++nj) {
#pragma unroll
      for (int mi = 0; mi < 2; ++mi) {
#pragma unroll
        for (int r = 0; r < 16; ++r) {
          const float v = acc[mi][nj][r];
          // must be !(v <= t): tminf is NaN while table has empty slots ->
          // fall through to exact u32 check ((v > NaN) starves; R2 bug).
          if (!(v <= tminf[nj])) {
            // 32x32 C/D: cb = (r&3) + 8*(r>>2) + 4*l5 within the mi-block
            const unsigned idx = (unsigned)(cfb0 + mi * 32 + (r & 3) + ((r >> 2) << 3));
            const unsigned key = (f2sortable(v) & ~0xFFFu) | idx;
            if (key > tkmin[nj]) {
              int ms = 0;
              unsigned mv = tk[nj][0];
#pragma unroll
              for (int q = 1; q < 8; ++q) { if (tk[nj][q] < mv) { mv = tk[nj][q]; ms = q; } }
#pragma unroll
              for (int q = 0; q < 8; ++q) tk[nj][q] = (q == ms) ? key : tk[nj][q];
              mv = tk[nj][0];
#pragma unroll
              for (int q = 1; q < 8; ++q) mv = (tk[nj][q] < mv) ? tk[nj][q] : mv;
              tkmin[nj] = mv;
              tminf[nj] = sortable2f(mv & ~0xFFFu);
            }
          }
          acc[mi][nj][r] = 0.f;
        }
      }
    }
  };

  // prologue: stage K-step 0 into buf0, advance pointers to K-step 1
  STAGE(0);
  zsp += BK; csp += BK;
  __syncthreads();

  for (int g = 0; g < GITERS; g += 2) {
    // even body: read buf0, stage K-step g+1 -> buf1
    STAGE(4096);
    zsp += BK; csp += BK;
    if (((g + 2) & 31) == 0) {            // next stage target crosses chunk
      zsp -= KSTEPS * BK;                 // Z tile repeats every chunk
      csp += MTILE * D_DIM - KSTEPS * BK; // C advances to next chunk slab
    }
    COMPUTE(0);
    __syncthreads();

    // odd body: read buf1, stage K-step g+2 -> buf0
    if (g + 2 < GITERS) {
      STAGE(0);
      zsp += BK; csp += BK;               // (g+3)&31 never 0 for even g
    }
    COMPUTE(4096);
    if ((g & 31) == 30) EPILOGUE((g + 1) >> 5);   // chunk完 at odd iters 31/63/95/127
    __syncthreads();
  }

  // merge: per z row 4 contributors (wc x l5) x 8 keys -> LDS, then top-8 scan
  unsigned* mrg = (unsigned*)smem;     // [128][33] u32 = 16.9 KB
  {
    const int slot = (wc * 2 + l5) * 8;
#pragma unroll
    for (int nj = 0; nj < 2; ++nj) {
      const int zrow = wzz * 64 + nj * 32 + l31;
#pragma unroll
      for (int q = 0; q < 8; ++q) mrg[zrow * 33 + slot + q] = tk[nj][q];
    }
  }
  __syncthreads();
  if (tid < MTILE) {
    const unsigned* c = mrg + tid * 33;
    unsigned top[8];
#pragma unroll
    for (int p = 0; p < 8; ++p) top[p] = 0u;
    unsigned tmin = 0u;
    for (int q0 = 0; q0 < 32; ++q0) {
      const unsigned k = c[(q0 + tid) & 31];   // rotate to spread banks
      if (k > tmin) {
        int ms = 0;
        unsigned mv = top[0];
#pragma unroll
        for (int q = 1; q < 8; ++q) { if (top[q] < mv) { mv = top[q]; ms = q; } }
#pragma unroll
        for (int q = 0; q < 8; ++q) top[q] = (q == ms) ? k : top[q];
        mv = top[0];
#pragma unroll
        for (int q = 1; q < 8; ++q) mv = (top[q] < mv) ? top[q] : mv;
        tmin = mv;
      }
    }
    unsigned* dst = part + ((size_t)(rbase + tid) * NS + split) * 8;
#pragma unroll
    for (int p = 0; p < 8; ++p) dst[p] = top[p];
  }
}

// ---------------- Kernel 3: merge splits, softmax, gather E, gate ----------------
template<int NSP>
__global__ __launch_bounds__(256)
void k_gate(const unsigned* __restrict__ part, const float* __restrict__ target,
            const float* __restrict__ E, float* __restrict__ out) {
  constexpr int NK = NSP * 8;
  const int row = blockIdx.x;
  const int t = threadIdx.x;
  __shared__ float s_alpha[8];
  __shared__ int s_idx[8];
  __shared__ unsigned s_key[8];

  if (t < NK) {
    unsigned k = part[(size_t)row * NK + t];
#pragma unroll
    for (int p = 0; p < 8; ++p) {
      unsigned m = k;
#pragma unroll
      for (int off = NK / 2; off > 0; off >>= 1) {
        const unsigned o = __shfl_xor(m, off, NK);
        m = (m > o) ? m : o;
      }
      if (k == m) { s_key[p] = k; k = 0u; }  // keys distinct (idx in low bits)
    }
  }
  __syncthreads();
  if (t < 8) {
    const unsigned key = s_key[t];
    const float val  = 10.0f * sortable2f(key & ~0xFFFu);
    const float vmax = 10.0f * sortable2f(s_key[0] & ~0xFFFu);
    const float e = expf(val - vmax);
    float s = e;
#pragma unroll
    for (int off = 4; off > 0; off >>= 1) s += __shfl_xor(s, off, 8);
    s_alpha[t] = e / s;
    s_idx[t] = (int)(key & 0xFFFu);
  }
  __syncthreads();

  float4 g = {0.f, 0.f, 0.f, 0.f};
#pragma unroll
  for (int p = 0; p < 8; ++p) {
    const float a = s_alpha[p];
    const float4 e4 = ((const float4*)E)[(size_t)s_idx[p] * 256 + t];
    g.x += a * e4.x;
    g.y += a * e4.y;
    g.z += a * e4.z;
    g.w += a * e4.w;
  }
  const float4 tg = ((const float4*)target)[(size_t)row * 256 + t];
  float4 o;
  o.x = tg.x * (1.f + g.x);
  o.y = tg.y * (1.f + g.y);
  o.z = tg.z * (1.f + g.z);
  o.w = tg.w * (1.f + g.w);
  ((float4*)out)[(size_t)row * 256 + t] = o;
}

extern "C" void kernel_launch(void* const* d_in, const int* in_sizes, int n_in,
                              void* d_out, int out_size, void* d_ws, size_t ws_size,
                              hipStream_t stream) {
  const float* z      = (const float*)d_in[0];
  const float* target = (const float*)d_in[1];
  const float* cb     = (const float*)d_in[2];
  const float* E      = (const float*)d_in[3];
  float* out = (float*)d_out;

  // d_out doubles as scratch for the bf16 normalized matrices (dead before k_gate writes)
  unsigned short* zf  = (unsigned short*)d_out;                       // 32 MB
  unsigned short* cbf = (unsigned short*)((char*)d_out + 33554432);   // 8 MB @ +32MB
  unsigned* part = (unsigned*)d_ws;                                   // 4 MB

  k_normalize<<<dim3(M_ROWS + K_CB), dim3(256), 0, stream>>>(z, cb, zf, cbf);
  k_gemm_topk<<<dim3(MBLOCKS * NS), dim3(256), 0, stream>>>(zf, cbf, part);
  k_gate<NS><<<dim3(M_ROWS), dim3(256), 0, stream>>>(part, target, E, out);
}